// Round 1
// baseline (651.925 us; speedup 1.0000x reference)
//
#include <hip/hip_runtime.h>
#include <math.h>

// Real spherical harmonics, l_max = 8, output [N, 81] f32.
// Strategy: 1 wave (64 threads) per block, 1 point per thread. Each thread
// computes its 81 values via the associated-Legendre + chebyshev-sincos
// recurrences, stores to an LDS tile (row stride 81 words: odd stride ->
// conflict-free), then the wave copies the contiguous 64*81-float tile to
// global as dense float4 stores (coalesced dwordx4).

namespace {

constexpr double csqrt(double x) {
    double g = x > 1.0 ? x : 1.0;
    for (int i = 0; i < 200; ++i) g = 0.5 * (g + x / g);
    return g;
}
constexpr double cfact(int n) {
    double r = 1.0;
    for (int i = 2; i <= n; ++i) r *= (double)i;
    return r;
}
constexpr double PI_D = 3.14159265358979323846264338327950288;

constexpr float coefv(int l, int m) {
    const int am = m < 0 ? -m : m;
    const double k = csqrt((2.0 * l + 1.0) / (4.0 * PI_D) * cfact(l - am) / cfact(l + am));
    const double s2 = 1.4142135623730950488016887242097;
    return (float)((m == 0 ? 1.0 : s2) * k);
}

struct CoefTab { float v[81]; };
constexpr CoefTab make_tab() {
    CoefTab t{};
    for (int l = 0; l <= 8; ++l)
        for (int m = -l; m <= l; ++m)
            t.v[l * l + l + m] = coefv(l, m);
    return t;
}
constexpr CoefTab COEF = make_tab();  // guaranteed compile-time

} // namespace

#define LMAX 8
#define NCOL 81                                   // (LMAX+1)^2
#define PTS_PER_BLOCK 64
#define FLOATS_PER_TILE (PTS_PER_BLOCK * NCOL)    // 5184 floats = 20736 B LDS
#define VEC4_PER_TILE (FLOATS_PER_TILE / 4)       // 1296 float4

__global__ __launch_bounds__(PTS_PER_BLOCK)
void sh_kernel(const float* __restrict__ ct_in, const float* __restrict__ phi_in,
               float* __restrict__ out, int n) {
    __shared__ __align__(16) float lds[FLOATS_PER_TILE];
    const int lane = threadIdx.x;                 // 0..63
    const long long tile = blockIdx.x;
    const long long idx = tile * PTS_PER_BLOCK + lane;

    if (idx < n) {
        const float ct = ct_in[idx];
        const float phi = phi_in[idx];
        const float st = sqrtf(fmaxf(1.0f - ct * ct, 0.0f));
        float sp, cp;
        __sincosf(phi, &sp, &cp);

        float* row = lds + lane * NCOL;           // word stride 81 (odd): conflict-free

        float pmm = 1.0f;                         // P(m,m)
        float cm = 1.0f;                          // cos(m*phi)
        float sm = 0.0f;                          // sin(m*phi)
#pragma unroll
        for (int m = 0; m <= LMAX; ++m) {
            if (m > 0) {
                pmm *= st * (float)(2 * m - 1);   // P(m,m) = P(m-1,m-1)*st*(2m-1)
                const float cn = cm * cp - sm * sp;
                const float sn = sm * cp + cm * sp;
                cm = cn; sm = sn;
            }
            // l = m
            {
                const int b = m * m + m;
                if (m == 0) {
                    row[b] = COEF.v[b] * pmm;
                } else {
                    row[b + m] = COEF.v[b + m] * pmm * cm;
                    row[b - m] = COEF.v[b - m] * pmm * sm;
                }
            }
            if (m < LMAX) {
                float p_prev = pmm;
                float p_cur = ct * (float)(2 * m + 1) * pmm;   // P(m+1,m)
                {
                    const int l = m + 1;
                    const int b = l * l + l;
                    if (m == 0) {
                        row[b] = COEF.v[b] * p_cur;
                    } else {
                        row[b + m] = COEF.v[b + m] * p_cur * cm;
                        row[b - m] = COEF.v[b - m] * p_cur * sm;
                    }
                }
#pragma unroll
                for (int l = m + 2; l <= LMAX; ++l) {
                    const float inv = 1.0f / (float)(l - m);
                    const float p_next = ((float)(2 * l - 1) * ct * p_cur
                                          - (float)(l + m - 1) * p_prev) * inv;
                    p_prev = p_cur; p_cur = p_next;
                    const int b = l * l + l;
                    if (m == 0) {
                        row[b] = COEF.v[b] * p_cur;
                    } else {
                        row[b + m] = COEF.v[b + m] * p_cur * cm;
                        row[b - m] = COEF.v[b - m] * p_cur * sm;
                    }
                }
            }
        }
    }
    __syncthreads();  // single wave; cheap — orders LDS writes vs cross-lane reads

    // Coalesced tile write: 5184 contiguous floats -> 1296 float4 (20 full
    // rounds of 64 lanes + 16-lane tail).
    float4* __restrict__ outv = (float4*)(out + tile * (long long)FLOATS_PER_TILE);
    const float4* lv = (const float4*)lds;
    const long long tile_base_f4 = tile * (long long)VEC4_PER_TILE;
    const long long total_f4 = ((long long)n * NCOL) / 4;
#pragma unroll
    for (int j = 0; j < 20; ++j) {
        const int e = j * 64 + lane;
        if (tile_base_f4 + e < total_f4) outv[e] = lv[e];
    }
    {
        const int e = 20 * 64 + lane;
        if (lane < 16 && tile_base_f4 + e < total_f4) outv[e] = lv[e];
    }
}

extern "C" void kernel_launch(void* const* d_in, const int* in_sizes, int n_in,
                              void* d_out, int out_size, void* d_ws, size_t ws_size,
                              hipStream_t stream) {
    const float* ct  = (const float*)d_in[1];
    const float* phi = (const float*)d_in[2];
    float* out = (float*)d_out;
    const int n = in_sizes[1];
    const int blocks = (n + PTS_PER_BLOCK - 1) / PTS_PER_BLOCK;  // 31250 exact
    sh_kernel<<<blocks, PTS_PER_BLOCK, 0, stream>>>(ct, phi, out, n);
}